// Round 4
// baseline (148.328 us; speedup 1.0000x reference)
//
#include <hip/hip_runtime.h>
#include <hip/hip_bf16.h>

// Match numpy float32 semantics exactly: no FMA contraction, fixed op order.
#pragma clang fp contract(off)

#define B_ 8
#define N_ 4096
#define C_ 128
#define K_ 16      // SAMPLE (output neighbors)
#define S_ 20      // SAMPLE_NUM (ball_query nsample)
#define NW 32      // queries per block -> 2KB contiguous per c-stream per block
#define NSUB 4     // queries per LDS pass (8 passes)
#define LP 69      // LDS row pitch in words: [c][LP]; 69 -> bank-conflict ~free

// slot s in [0,20) -> output position k = s - 1 - s/5, valid iff s>0 && s%5!=0

__global__ __launch_bounds__(256) void fused_kernel(const float* __restrict__ xyz,
                                                    const float* __restrict__ feat,
                                                    float* __restrict__ out_xyz,
                                                    float* __restrict__ out_feat) {
#pragma clang fp contract(off)
    __shared__ float lds[C_ * LP];      // 35.3 KB transpose buffer (reused 8x)
    __shared__ int sidx[NW * K_];       // 2 KB

    const int w    = blockIdx.x;        // 0..1023
    const int b    = w & 7;             // XCD-align: batch b lives on XCD b
    const int n0   = (w >> 3) * NW;     // 0,32,..,4064
    const int t    = threadIdx.x;
    const int wave = t >> 6;
    const int lane = t & 63;
    const float* xb = xyz + (size_t)b * N_ * 3;

    // ---------------- Phase A: ball query, 8 sequential queries per wave ----
    {
        // chunk-0 candidate coords cached once (same for all 8 queries)
        const float c0x = xb[lane * 3 + 0];
        const float c0y = xb[lane * 3 + 1];
        const float c0z = xb[lane * 3 + 2];

        for (int j = 0; j < NW / 4; ++j) {
            const int nq = wave * (NW / 4) + j;
            const int n  = n0 + nq;
            const float qx = xb[n * 3 + 0];
            const float qy = xb[n * 3 + 1];
            const float qz = xb[n * 3 + 2];
            const float sqn = (qx * qx + qy * qy) + qz * qz;

            int cnt = 0;
            int first = -1;
            int* out = sidx + nq * K_;

            float cx = c0x, cy = c0y, cz = c0z;
            for (int base = 0; base < N_; base += 64) {
                // software prefetch of next chunk (hides L2 latency under ALU)
                const int nb = base + 64;
                float px = 0.f, py = 0.f, pz = 0.f;
                if (nb < N_) {
                    px = xb[(nb + lane) * 3 + 0];
                    py = xb[(nb + lane) * 3 + 1];
                    pz = xb[(nb + lane) * 3 + 2];
                }

                const int m = base + lane;
                const float sqm = (cx * cx + cy * cy) + cz * cz;
                const float dot = (qx * cx + qy * cy) + qz * cz;
                const float d2  = (sqn + sqm) - 2.0f * dot;
                const bool in = d2 < 256.0f;

                const unsigned long long mask = __ballot(in);
                if (cnt == 0 && mask != 0ull) {
                    first = base + __builtin_ctzll(mask);   // wave-uniform
                }
                const int pre  = __popcll(mask & ((1ull << lane) - 1ull));
                const int slot = cnt + pre;
                if (in && slot < S_ && slot > 0 && (slot % 5) != 0) {
                    out[slot - 1 - slot / 5] = m;
                }
                cnt += __popcll(mask);        // wave-uniform
                if (cnt >= S_) break;         // wave-uniform exit
                cx = px; cy = py; cz = pz;
            }

            // pad slots [cnt, 20) with 'first'
            if (lane < S_ && lane >= cnt && lane > 0 && (lane % 5) != 0) {
                out[lane - 1 - lane / 5] = first;
            }
        }
    }
    __syncthreads();   // sidx visible to all waves

    // ---------------- xyz gather: 3*32*16 floats, 2KB contiguous per j ------
    for (int e = t; e < 3 * NW * K_; e += 256) {
        const int j  = e >> 9;            // 0..2
        const int r9 = e & 511;           // nl*16+k
        const int nl = r9 >> 4;
        const int k  = r9 & 15;
        out_xyz[((size_t)(b * 3 + j) * N_ + (n0 + nl)) * K_ + k] =
            xb[sidx[nl * K_ + k] * 3 + j];
    }

    // ---------------- feature gather: 8 sub-tiles of 4 queries --------------
    const float* fb = feat + (size_t)b * N_ * C_;
    float* ob = out_feat + (size_t)b * C_ * N_ * K_ + (size_t)n0 * K_;

    for (int st = 0; st < NW / NSUB; ++st) {
        __syncthreads();   // previous drain finished reading lds
        // stage: 64 rows (4 queries x 16 nbrs) of 512 B, float4 global loads
        for (int f = t; f < NSUB * K_ * C_ / 4; f += 256) {   // 2048 float4
            const int r  = f >> 5;            // 0..63 = nl*16+k
            const int c0 = (f & 31) * 4;
            const int row = sidx[(st * NSUB + (r >> 4)) * K_ + (r & 15)];
            const float4 v =
                *reinterpret_cast<const float4*>(fb + (size_t)row * C_ + c0);
            lds[(c0 + 0) * LP + r] = v.x;
            lds[(c0 + 1) * LP + r] = v.y;
            lds[(c0 + 2) * LP + r] = v.z;
            lds[(c0 + 3) * LP + r] = v.w;
        }
        __syncthreads();
        // drain: per c, 64 consecutive dwords (4n x 16k) = 256 B per wave,
        // 8 consecutive sub-tiles -> 2 KB contiguous per c-stream per block
        for (int e = t; e < NSUB * K_ * C_; e += 256) {
            const int c = e >> 6;             // wave-uniform
            const int r = e & 63;             // = lane
            ob[(size_t)c * (N_ * K_) + (size_t)(st * NSUB) * K_ + r] =
                lds[c * LP + r];
        }
    }
}

extern "C" void kernel_launch(void* const* d_in, const int* in_sizes, int n_in,
                              void* d_out, int out_size, void* d_ws, size_t ws_size,
                              hipStream_t stream) {
    const float* xyz  = (const float*)d_in[0];   // (8, 4096, 3)
    const float* feat = (const float*)d_in[1];   // (8, 4096, 128)

    float* out_xyz  = (float*)d_out;                       // (8,3,4096,16)
    float* out_feat = out_xyz + (size_t)B_ * 3 * N_ * K_;  // (8,128,4096,16)

    // one block per (b, 32 consecutive queries); fused, no workspace
    hipLaunchKernelGGL(fused_kernel, dim3(B_ * N_ / NW), dim3(256), 0, stream,
                       xyz, feat, out_xyz, out_feat);
}

// Round 5
// 112.284 us; speedup vs baseline: 1.3210x; 1.3210x over previous
//
#include <hip/hip_runtime.h>
#include <hip/hip_bf16.h>

// Match numpy float32 semantics exactly: no FMA contraction, fixed op order.
#pragma clang fp contract(off)

#define B_ 8
#define N_ 4096
#define C_ 128
#define K_ 16      // SAMPLE (output neighbors)
#define S_ 20      // SAMPLE_NUM (ball_query nsample)
#define NW 32      // queries per block -> 2KB contiguous per c-stream per block
#define NSUB 4     // queries per LDS pass (8 passes), r = NSUB*K = 64 rows
#define LP 129     // LDS pitch in words for [r][LP]: odd -> drain reads conflict-free

// slot s in [0,20) -> output position k = s - 1 - s/5, valid iff s>0 && s%5!=0

__global__ __launch_bounds__(512, 8) void fused_kernel(const float* __restrict__ xyz,
                                                       const float* __restrict__ feat,
                                                       float* __restrict__ out_xyz,
                                                       float* __restrict__ out_feat) {
#pragma clang fp contract(off)
    __shared__ float lds[NSUB * K_ * LP];   // 64 x 129 words = 33 KB, reused 8x
    __shared__ int sidx[NW * K_];           // 2 KB

    const int w    = blockIdx.x;        // 0..1023
    const int b    = w & 7;             // XCD-align: batch b lives on XCD b
    const int n0   = (w >> 3) * NW;     // 0,32,..,4064
    const int t    = threadIdx.x;       // 0..511
    const int wave = t >> 6;            // 0..7
    const int lane = t & 63;
    const float* xb = xyz + (size_t)b * N_ * 3;

    // ---------------- Phase A: ball query, 4 sequential queries per wave ----
    {
        // chunk-0 candidate coords cached once (same for all queries)
        const float c0x = xb[lane * 3 + 0];
        const float c0y = xb[lane * 3 + 1];
        const float c0z = xb[lane * 3 + 2];

        for (int j = 0; j < NW / 8; ++j) {
            const int nq = wave * (NW / 8) + j;
            const int n  = n0 + nq;
            const float qx = xb[n * 3 + 0];
            const float qy = xb[n * 3 + 1];
            const float qz = xb[n * 3 + 2];
            const float sqn = (qx * qx + qy * qy) + qz * qz;

            int cnt = 0;
            int first = -1;
            int* out = sidx + nq * K_;

            float cx = c0x, cy = c0y, cz = c0z;
            for (int base = 0; base < N_; base += 64) {
                // software prefetch of next chunk (hides L2 latency under ALU)
                const int nb = base + 64;
                float px = 0.f, py = 0.f, pz = 0.f;
                if (nb < N_) {
                    px = xb[(nb + lane) * 3 + 0];
                    py = xb[(nb + lane) * 3 + 1];
                    pz = xb[(nb + lane) * 3 + 2];
                }

                const int m = base + lane;
                const float sqm = (cx * cx + cy * cy) + cz * cz;
                const float dot = (qx * cx + qy * cy) + qz * cz;
                const float d2  = (sqn + sqm) - 2.0f * dot;
                const bool in = d2 < 256.0f;

                const unsigned long long mask = __ballot(in);
                if (cnt == 0 && mask != 0ull) {
                    first = base + __builtin_ctzll(mask);   // wave-uniform
                }
                const int pre  = __popcll(mask & ((1ull << lane) - 1ull));
                const int slot = cnt + pre;
                if (in && slot < S_ && slot > 0 && (slot % 5) != 0) {
                    out[slot - 1 - slot / 5] = m;
                }
                cnt += __popcll(mask);        // wave-uniform
                if (cnt >= S_) break;         // wave-uniform exit
                cx = px; cy = py; cz = pz;
            }

            // pad slots [cnt, 20) with 'first'
            if (lane < S_ && lane >= cnt && lane > 0 && (lane % 5) != 0) {
                out[lane - 1 - lane / 5] = first;
            }
        }
    }
    __syncthreads();   // sidx visible to all waves

    // ---------------- xyz gather: 3*32*16 floats, 2KB contiguous per j ------
    for (int e = t; e < 3 * NW * K_; e += 512) {
        const int j  = e >> 9;            // 0..2
        const int r9 = e & 511;           // nl*16+k
        const int nl = r9 >> 4;
        const int k  = r9 & 15;
        out_xyz[((size_t)(b * 3 + j) * N_ + (n0 + nl)) * K_ + k] =
            xb[sidx[nl * K_ + k] * 3 + j];
    }

    // ---------------- feature gather: 8 sub-tiles of 4 queries --------------
    const float* fb = feat + (size_t)b * N_ * C_;
    float* ob = out_feat + (size_t)b * C_ * N_ * K_ + (size_t)n0 * K_;

    for (int st = 0; st < NW / NSUB; ++st) {
        __syncthreads();   // previous drain finished reading lds
        // stage: 64 rows (4 queries x 16 nbrs) of 512 B via float4 loads,
        // row-major lds[r][c] pitch 129: write banks 4-way (1.58x), cheap
        for (int f = t; f < NSUB * K_ * C_ / 4; f += 512) {   // 2048 float4
            const int r  = f >> 5;            // 0..63 = nl*16+k
            const int c0 = (f & 31) * 4;
            const int row = sidx[(st * NSUB + (r >> 4)) * K_ + (r & 15)];
            const float4 v =
                *reinterpret_cast<const float4*>(fb + (size_t)row * C_ + c0);
            lds[r * LP + c0 + 0] = v.x;
            lds[r * LP + c0 + 1] = v.y;
            lds[r * LP + c0 + 2] = v.z;
            lds[r * LP + c0 + 3] = v.w;
        }
        __syncthreads();
        // drain: per c, 64 consecutive dwords (4n x 16k) = 256 B per wave inst;
        // LDS read bank = (lane + c) % 32 -> 2-way, free.
        for (int e = t; e < NSUB * K_ * C_; e += 512) {
            const int c = e >> 6;             // wave-uniform per inst
            const int r = e & 63;             // = lane
            ob[(size_t)c * (N_ * K_) + (size_t)(st * NSUB) * K_ + r] =
                lds[r * LP + c];
        }
    }
}

extern "C" void kernel_launch(void* const* d_in, const int* in_sizes, int n_in,
                              void* d_out, int out_size, void* d_ws, size_t ws_size,
                              hipStream_t stream) {
    const float* xyz  = (const float*)d_in[0];   // (8, 4096, 3)
    const float* feat = (const float*)d_in[1];   // (8, 4096, 128)

    float* out_xyz  = (float*)d_out;                       // (8,3,4096,16)
    float* out_feat = out_xyz + (size_t)B_ * 3 * N_ * K_;  // (8,128,4096,16)

    // one block per (b, 32 consecutive queries); 8 waves; fused, no workspace
    hipLaunchKernelGGL(fused_kernel, dim3(B_ * N_ / NW), dim3(512), 0, stream,
                       xyz, feat, out_xyz, out_feat);
}

// Round 6
// 93.449 us; speedup vs baseline: 1.5873x; 1.2016x over previous
//
#include <hip/hip_runtime.h>
#include <hip/hip_bf16.h>

// Match numpy float32 semantics exactly: no FMA contraction, fixed op order.
#pragma clang fp contract(off)

#define B_ 8
#define N_ 4096
#define C_ 128
#define K_ 16      // SAMPLE (output neighbors)
#define S_ 20      // SAMPLE_NUM (ball_query nsample)
#define NW 32      // queries per block
#define NSUB 4     // queries per LDS transpose pass (8 passes)
#define LP 129     // transpose pitch (words): odd -> drain reads conflict-free
#define THREADS 512

// slot s in [0,20) -> output position k = s - 1 - s/5, valid iff s>0 && s%5!=0

__global__ __launch_bounds__(THREADS, 4) void fused_kernel(const float* __restrict__ xyz,
                                                           const float* __restrict__ feat,
                                                           float* __restrict__ out_xyz,
                                                           float* __restrict__ out_feat) {
#pragma clang fp contract(off)
    // 48 KB union: phase A = whole-batch xyz cache; phase B = transpose buffer
    __shared__ float smem[N_ * 3];
    __shared__ int sidx[NW * K_];

    const int w    = blockIdx.x;        // 0..1023
    const int b    = w & 7;             // XCD-align: batch b lives on XCD b
    const int n0   = (w >> 3) * NW;
    const int t    = threadIdx.x;
    const int wave = t >> 6;            // 0..7
    const int lane = t & 63;
    const float* xb = xyz + (size_t)b * (N_ * 3);

    // ---- stage whole batch xyz into LDS (3072 float4 = 48 KB, coalesced) ----
    {
        const float4* src = reinterpret_cast<const float4*>(xb);
        float4* dst = reinterpret_cast<float4*>(smem);
        for (int i = t; i < N_ * 3 / 4; i += THREADS) dst[i] = src[i];
    }
    __syncthreads();

    // ---------------- Phase A: 4 queries/wave, 4 candidates/lane/iter -------
    for (int jq = 0; jq < NW / 8; ++jq) {
        const int nq = wave * (NW / 8) + jq;
        const int n  = n0 + nq;
        const float qx = smem[n * 3 + 0];
        const float qy = smem[n * 3 + 1];
        const float qz = smem[n * 3 + 2];
        const float sqn = (qx * qx + qy * qy) + qz * qz;

        int cnt = 0;
        int first = -1;
        int* out = sidx + nq * K_;
        const unsigned long long below = (1ull << lane) - 1ull;

        for (int base = 0; base < N_; base += 256) {
            const int m0 = base + 4 * lane;
            // 48 contiguous bytes per lane: 3 x ds_read_b128, ~conflict-free
            const float4 A  = *reinterpret_cast<const float4*>(&smem[m0 * 3 + 0]);
            const float4 Bv = *reinterpret_cast<const float4*>(&smem[m0 * 3 + 4]);
            const float4 Cv = *reinterpret_cast<const float4*>(&smem[m0 * 3 + 8]);

            const float x0 = A.x,  y0 = A.y,  z0 = A.z;
            const float x1 = A.w,  y1 = Bv.x, z1 = Bv.y;
            const float x2 = Bv.z, y2 = Bv.w, z2 = Cv.x;
            const float x3 = Cv.y, y3 = Cv.z, z3 = Cv.w;

            bool in0, in1, in2, in3;
            { const float sq = (x0*x0 + y0*y0) + z0*z0, dt = (qx*x0 + qy*y0) + qz*z0;
              in0 = ((sqn + sq) - 2.0f * dt) < 256.0f; }
            { const float sq = (x1*x1 + y1*y1) + z1*z1, dt = (qx*x1 + qy*y1) + qz*z1;
              in1 = ((sqn + sq) - 2.0f * dt) < 256.0f; }
            { const float sq = (x2*x2 + y2*y2) + z2*z2, dt = (qx*x2 + qy*y2) + qz*z2;
              in2 = ((sqn + sq) - 2.0f * dt) < 256.0f; }
            { const float sq = (x3*x3 + y3*y3) + z3*z3, dt = (qx*x3 + qy*y3) + qz*z3;
              in3 = ((sqn + sq) - 2.0f * dt) < 256.0f; }

            const unsigned long long M0 = __ballot(in0);
            const unsigned long long M1 = __ballot(in1);
            const unsigned long long M2 = __ballot(in2);
            const unsigned long long M3 = __ballot(in3);

            if (cnt == 0) {   // wave-uniform
                int f = 0x7fffffff;
                if (M0) { const int c = base + 4 * (int)__builtin_ctzll(M0) + 0; f = f < c ? f : c; }
                if (M1) { const int c = base + 4 * (int)__builtin_ctzll(M1) + 1; f = f < c ? f : c; }
                if (M2) { const int c = base + 4 * (int)__builtin_ctzll(M2) + 2; f = f < c ? f : c; }
                if (M3) { const int c = base + 4 * (int)__builtin_ctzll(M3) + 3; f = f < c ? f : c; }
                if (f != 0x7fffffff) first = f;
            }

            // in-order slot: all j at lanes < l, plus j' < j at this lane
            const int p = __popcll(M0 & below) + __popcll(M1 & below)
                        + __popcll(M2 & below) + __popcll(M3 & below);
            const int b0 = (int)((M0 >> lane) & 1);
            const int b1 = (int)((M1 >> lane) & 1);
            const int b2 = (int)((M2 >> lane) & 1);
            const int s0 = cnt + p;
            const int s1 = s0 + b0;
            const int s2 = s1 + b1;
            const int s3 = s2 + b2;
            if (in0 && s0 > 0 && s0 < S_ && (s0 % 5) != 0) out[s0 - 1 - s0 / 5] = m0 + 0;
            if (in1 && s1 > 0 && s1 < S_ && (s1 % 5) != 0) out[s1 - 1 - s1 / 5] = m0 + 1;
            if (in2 && s2 > 0 && s2 < S_ && (s2 % 5) != 0) out[s2 - 1 - s2 / 5] = m0 + 2;
            if (in3 && s3 > 0 && s3 < S_ && (s3 % 5) != 0) out[s3 - 1 - s3 / 5] = m0 + 3;

            cnt += __popcll(M0) + __popcll(M1) + __popcll(M2) + __popcll(M3);
            if (cnt >= S_) break;   // wave-uniform exit
        }

        // pad slots [cnt, 20) with 'first'
        if (lane < S_ && lane >= cnt && lane > 0 && (lane % 5) != 0) {
            out[lane - 1 - lane / 5] = first;
        }
    }
    __syncthreads();   // sidx complete; smem(xyz) still needed below

    // ---------------- xyz gather (reads smem + sidx) ------------------------
    for (int e = t; e < 3 * NW * K_; e += THREADS) {
        const int j  = e >> 9;            // 0..2
        const int r9 = e & 511;
        const int nl = r9 >> 4;
        const int k  = r9 & 15;
        out_xyz[((size_t)(b * 3 + j) * N_ + (n0 + nl)) * K_ + k] =
            smem[sidx[nl * K_ + k] * 3 + j];
    }
    __syncthreads();   // done reading smem as xyz; reuse as transpose buffer

    // ---------------- feature gather: 8 sub-tiles of 4 queries --------------
    const float* fb = feat + (size_t)b * N_ * C_;
    float* ob = out_feat + (size_t)b * C_ * N_ * K_ + (size_t)n0 * K_;

    for (int st = 0; st < NW / NSUB; ++st) {
        if (st) __syncthreads();   // previous drain finished reading smem
        // stage: 64 rows (4 queries x 16 nbrs) of 512 B via float4 loads
        for (int f = t; f < NSUB * K_ * C_ / 4; f += THREADS) {   // 2048 float4
            const int r  = f >> 5;            // 0..63 = nl*16+k
            const int c0 = (f & 31) * 4;
            const int row = sidx[(st * NSUB + (r >> 4)) * K_ + (r & 15)];
            const float4 v =
                *reinterpret_cast<const float4*>(fb + (size_t)row * C_ + c0);
            smem[r * LP + c0 + 0] = v.x;
            smem[r * LP + c0 + 1] = v.y;
            smem[r * LP + c0 + 2] = v.z;
            smem[r * LP + c0 + 3] = v.w;
        }
        __syncthreads();
        // drain: per c, 64 consecutive dwords = 256 B per wave inst;
        // LDS read bank = (lane + c) % 32 -> 2-way, free.
        for (int e = t; e < NSUB * K_ * C_; e += THREADS) {
            const int c = e >> 6;             // wave-uniform per inst
            const int r = e & 63;             // = lane
            ob[(size_t)c * (N_ * K_) + (size_t)(st * NSUB) * K_ + r] =
                smem[r * LP + c];
        }
    }
}

extern "C" void kernel_launch(void* const* d_in, const int* in_sizes, int n_in,
                              void* d_out, int out_size, void* d_ws, size_t ws_size,
                              hipStream_t stream) {
    const float* xyz  = (const float*)d_in[0];   // (8, 4096, 3)
    const float* feat = (const float*)d_in[1];   // (8, 4096, 128)

    float* out_xyz  = (float*)d_out;                       // (8,3,4096,16)
    float* out_feat = out_xyz + (size_t)B_ * 3 * N_ * K_;  // (8,128,4096,16)

    // one block per (b, 32 consecutive queries); fused, no workspace
    hipLaunchKernelGGL(fused_kernel, dim3(B_ * N_ / NW), dim3(THREADS), 0, stream,
                       xyz, feat, out_xyz, out_feat);
}

// Round 7
// 89.530 us; speedup vs baseline: 1.6567x; 1.0438x over previous
//
#include <hip/hip_runtime.h>
#include <hip/hip_bf16.h>

// Match numpy float32 semantics exactly: no FMA contraction, fixed op order.
#pragma clang fp contract(off)

#define B_ 8
#define N_ 4096
#define C_ 128
#define K_ 16      // SAMPLE (output neighbors)
#define S_ 20      // SAMPLE_NUM (ball_query nsample)
#define NW 32      // queries per block
#define NSUB 4     // queries per LDS transpose pass (8 passes)
#define LP 129     // transpose pitch (words): odd -> drain reads conflict-free
#define THREADS 512

// slot s in [0,20) -> output position k = s - 1 - s/5, valid iff s>0 && s%5!=0

__global__ __launch_bounds__(THREADS, 6) void fused_kernel(const float* __restrict__ xyz,
                                                           const float* __restrict__ feat,
                                                           float* __restrict__ out_xyz,
                                                           float* __restrict__ out_feat) {
#pragma clang fp contract(off)
    // 48 KB union: phase A = whole-batch xyz cache; phase B = transpose buffer
    __shared__ float smem[N_ * 3];
    __shared__ int sidx[NW * K_];

    const int w    = blockIdx.x;        // 0..1023
    const int b    = w & 7;             // XCD-align: batch b lives on XCD b
    const int n0   = (w >> 3) * NW;
    const int t    = threadIdx.x;
    const int wave = t >> 6;            // 0..7
    const int lane = t & 63;
    const float* xb = xyz + (size_t)b * (N_ * 3);

    // ---- stage whole batch xyz into LDS (3072 float4 = 48 KB, coalesced) ----
    {
        const float4* src = reinterpret_cast<const float4*>(xb);
        float4* dst = reinterpret_cast<float4*>(smem);
        for (int i = t; i < N_ * 3 / 4; i += THREADS) dst[i] = src[i];
    }
    __syncthreads();

    // ---------------- Phase A: 4 queries/wave, 8 candidates/lane/iter -------
    for (int jq = 0; jq < NW / 8; ++jq) {
        const int nq = wave * (NW / 8) + jq;
        const int n  = n0 + nq;
        const float qx = smem[n * 3 + 0];
        const float qy = smem[n * 3 + 1];
        const float qz = smem[n * 3 + 2];
        const float sqn = (qx * qx + qy * qy) + qz * qz;

        int cnt = 0;
        int first = -1;
        int* out = sidx + nq * K_;
        const unsigned long long below = (1ull << lane) - 1ull;

        for (int base = 0; base < N_; base += 512) {
            const int m0 = base + 8 * lane;
            // 96 contiguous bytes per lane: 6 x ds_read_b128 (16B-aligned)
            const float4 A = *reinterpret_cast<const float4*>(&smem[m0 * 3 + 0]);
            const float4 Bv= *reinterpret_cast<const float4*>(&smem[m0 * 3 + 4]);
            const float4 Cv= *reinterpret_cast<const float4*>(&smem[m0 * 3 + 8]);
            const float4 Dv= *reinterpret_cast<const float4*>(&smem[m0 * 3 + 12]);
            const float4 Ev= *reinterpret_cast<const float4*>(&smem[m0 * 3 + 16]);
            const float4 Fv= *reinterpret_cast<const float4*>(&smem[m0 * 3 + 20]);

            const float X[8] = {A.x, A.w, Bv.z, Cv.y, Dv.x, Dv.w, Ev.z, Fv.y};
            const float Y[8] = {A.y, Bv.x, Bv.w, Cv.z, Dv.y, Ev.x, Ev.w, Fv.z};
            const float Z[8] = {A.z, Bv.y, Cv.x, Cv.w, Dv.z, Ev.y, Fv.x, Fv.w};

            bool in[8];
#pragma unroll
            for (int i = 0; i < 8; ++i) {
                const float sq = (X[i] * X[i] + Y[i] * Y[i]) + Z[i] * Z[i];
                const float dt = (qx * X[i] + qy * Y[i]) + qz * Z[i];
                in[i] = ((sqn + sq) - 2.0f * dt) < 256.0f;
            }

            unsigned long long M[8];
#pragma unroll
            for (int i = 0; i < 8; ++i) M[i] = __ballot(in[i]);

            if (cnt == 0) {   // wave-uniform: find global first in-ball index
                int f = 0x7fffffff;
#pragma unroll
                for (int i = 0; i < 8; ++i) {
                    if (M[i]) {
                        const int c = base + 8 * (int)__builtin_ctzll(M[i]) + i;
                        f = f < c ? f : c;
                    }
                }
                if (f != 0x7fffffff) first = f;
            }

            // in-order slot: all hits at lanes < l (any i), plus i' < i here
            int p = cnt;
#pragma unroll
            for (int i = 0; i < 8; ++i) p += (int)__popcll(M[i] & below);
            int s = p;
#pragma unroll
            for (int i = 0; i < 8; ++i) {
                if (in[i]) {
                    if (s > 0 && s < S_ && (s % 5) != 0)
                        out[s - 1 - s / 5] = m0 + i;
                    s += 1;
                }
            }

#pragma unroll
            for (int i = 0; i < 8; ++i) cnt += (int)__popcll(M[i]);
            if (cnt >= S_) break;   // wave-uniform exit
        }

        // pad slots [cnt, 20) with 'first'
        if (lane < S_ && lane >= cnt && lane > 0 && (lane % 5) != 0) {
            out[lane - 1 - lane / 5] = first;
        }
    }
    __syncthreads();   // sidx complete; smem(xyz) still needed below

    // ---------------- xyz gather (reads smem + sidx) ------------------------
    for (int e = t; e < 3 * NW * K_; e += THREADS) {
        const int j  = e >> 9;            // 0..2
        const int r9 = e & 511;
        const int nl = r9 >> 4;
        const int k  = r9 & 15;
        out_xyz[((size_t)(b * 3 + j) * N_ + (n0 + nl)) * K_ + k] =
            smem[sidx[nl * K_ + k] * 3 + j];
    }

    // ---------------- feature gather: 8 sub-tiles, software-pipelined -------
    const float* fb = feat + (size_t)b * N_ * C_;
    float* ob = out_feat + (size_t)b * C_ * N_ * K_ + (size_t)n0 * K_;

    // per-thread tile slice: 4 float4 (rows r = (t+512i)>>5, cols c0 = (t&31)*4)
    float4 v0, v1, v2, v3;
    const int rr0 = t >> 5,        cc0 = (t & 31) * 4;
    const int rr1 = (t + 512) >> 5;
    const int rr2 = (t + 1024) >> 5;
    const int rr3 = (t + 1536) >> 5;

#define LOADREGS(ST)                                                            \
    do {                                                                        \
        const int s_ = (ST) * NSUB;                                             \
        v0 = *reinterpret_cast<const float4*>(                                  \
            fb + (size_t)sidx[(s_ + (rr0 >> 4)) * K_ + (rr0 & 15)] * C_ + cc0); \
        v1 = *reinterpret_cast<const float4*>(                                  \
            fb + (size_t)sidx[(s_ + (rr1 >> 4)) * K_ + (rr1 & 15)] * C_ + cc0); \
        v2 = *reinterpret_cast<const float4*>(                                  \
            fb + (size_t)sidx[(s_ + (rr2 >> 4)) * K_ + (rr2 & 15)] * C_ + cc0); \
        v3 = *reinterpret_cast<const float4*>(                                  \
            fb + (size_t)sidx[(s_ + (rr3 >> 4)) * K_ + (rr3 & 15)] * C_ + cc0); \
    } while (0)

    LOADREGS(0);   // prologue (reads sidx + global only; smem untouched)

    for (int st = 0; st < NW / NSUB; ++st) {
        __syncthreads();   // previous drain (or xyz gather) done reading smem
        // commit tile st from regs into transpose buffer
        smem[rr0 * LP + cc0 + 0] = v0.x; smem[rr0 * LP + cc0 + 1] = v0.y;
        smem[rr0 * LP + cc0 + 2] = v0.z; smem[rr0 * LP + cc0 + 3] = v0.w;
        smem[rr1 * LP + cc0 + 0] = v1.x; smem[rr1 * LP + cc0 + 1] = v1.y;
        smem[rr1 * LP + cc0 + 2] = v1.z; smem[rr1 * LP + cc0 + 3] = v1.w;
        smem[rr2 * LP + cc0 + 0] = v2.x; smem[rr2 * LP + cc0 + 1] = v2.y;
        smem[rr2 * LP + cc0 + 2] = v2.z; smem[rr2 * LP + cc0 + 3] = v2.w;
        smem[rr3 * LP + cc0 + 0] = v3.x; smem[rr3 * LP + cc0 + 1] = v3.y;
        smem[rr3 * LP + cc0 + 2] = v3.z; smem[rr3 * LP + cc0 + 3] = v3.w;

        if (st + 1 < NW / NSUB) LOADREGS(st + 1);   // L2 latency hides under drain

        __syncthreads();
        // drain: per c, 64 consecutive dwords = 256 B per wave inst;
        // LDS read bank = (lane + c) % 32 -> 2-way, free.
        for (int e = t; e < NSUB * K_ * C_; e += THREADS) {
            const int c = e >> 6;             // wave-uniform per inst
            const int r = e & 63;             // = lane
            ob[(size_t)c * (N_ * K_) + (size_t)(st * NSUB) * K_ + r] =
                smem[r * LP + c];
        }
    }
#undef LOADREGS
}

extern "C" void kernel_launch(void* const* d_in, const int* in_sizes, int n_in,
                              void* d_out, int out_size, void* d_ws, size_t ws_size,
                              hipStream_t stream) {
    const float* xyz  = (const float*)d_in[0];   // (8, 4096, 3)
    const float* feat = (const float*)d_in[1];   // (8, 4096, 128)

    float* out_xyz  = (float*)d_out;                       // (8,3,4096,16)
    float* out_feat = out_xyz + (size_t)B_ * 3 * N_ * K_;  // (8,128,4096,16)

    // one block per (b, 32 consecutive queries); fused, no workspace
    hipLaunchKernelGGL(fused_kernel, dim3(B_ * N_ / NW), dim3(THREADS), 0, stream,
                       xyz, feat, out_xyz, out_feat);
}

// Round 8
// 79.948 us; speedup vs baseline: 1.8553x; 1.1199x over previous
//
#include <hip/hip_runtime.h>
#include <hip/hip_bf16.h>

// Match numpy float32 semantics exactly: no FMA contraction, fixed op order.
#pragma clang fp contract(off)

#define B_ 8
#define N_ 4096
#define C_ 128
#define K_ 16      // SAMPLE (output neighbors)
#define S_ 20      // SAMPLE_NUM (ball_query nsample)
#define NW 32      // queries per block
#define NSUB 4     // queries per LDS transpose pass (8 passes)
#define LP 129     // transpose pitch (words): odd -> conflict-light both sides
#define THREADS 512

typedef float f4 __attribute__((ext_vector_type(4)));

// slot s in [0,20) -> output position k = s - 1 - s/5, valid iff s>0 && s%5!=0

__global__ __launch_bounds__(THREADS, 6) void fused_kernel(const float* __restrict__ xyz,
                                                           const float* __restrict__ feat,
                                                           float* __restrict__ out_xyz,
                                                           float* __restrict__ out_feat) {
#pragma clang fp contract(off)
    // 48 KB union: phase A = whole-batch xyz cache; phase B = transpose buffer
    __shared__ float smem[N_ * 3];
    __shared__ int sidx[NW * K_];

    const int w    = blockIdx.x;        // 0..1023
    const int b    = w & 7;             // XCD-align: batch b lives on XCD b
    const int n0   = (w >> 3) * NW;
    const int t    = threadIdx.x;
    const int wave = t >> 6;            // 0..7
    const int lane = t & 63;
    const float* xb = xyz + (size_t)b * (N_ * 3);

    // ---- stage whole batch xyz into LDS (3072 float4 = 48 KB, coalesced) ----
    {
        const f4* src = reinterpret_cast<const f4*>(xb);
        f4* dst = reinterpret_cast<f4*>(smem);
        for (int i = t; i < N_ * 3 / 4; i += THREADS) dst[i] = src[i];
    }
    __syncthreads();

    // ---------------- Phase A: 4 queries/wave, 8 candidates/lane/iter -------
    for (int jq = 0; jq < NW / 8; ++jq) {
        const int nq = wave * (NW / 8) + jq;
        const int n  = n0 + nq;
        const float qx = smem[n * 3 + 0];
        const float qy = smem[n * 3 + 1];
        const float qz = smem[n * 3 + 2];
        const float sqn = (qx * qx + qy * qy) + qz * qz;

        int cnt = 0;
        int first = -1;
        int* out = sidx + nq * K_;
        const unsigned long long below = (1ull << lane) - 1ull;

        for (int base = 0; base < N_; base += 512) {
            const int m0 = base + 8 * lane;
            // 96 contiguous bytes per lane: 6 x ds_read_b128 (16B-aligned)
            const f4 A = *reinterpret_cast<const f4*>(&smem[m0 * 3 + 0]);
            const f4 Bv= *reinterpret_cast<const f4*>(&smem[m0 * 3 + 4]);
            const f4 Cv= *reinterpret_cast<const f4*>(&smem[m0 * 3 + 8]);
            const f4 Dv= *reinterpret_cast<const f4*>(&smem[m0 * 3 + 12]);
            const f4 Ev= *reinterpret_cast<const f4*>(&smem[m0 * 3 + 16]);
            const f4 Fv= *reinterpret_cast<const f4*>(&smem[m0 * 3 + 20]);

            const float X[8] = {A.x, A.w, Bv.z, Cv.y, Dv.x, Dv.w, Ev.z, Fv.y};
            const float Y[8] = {A.y, Bv.x, Bv.w, Cv.z, Dv.y, Ev.x, Ev.w, Fv.z};
            const float Z[8] = {A.z, Bv.y, Cv.x, Cv.w, Dv.z, Ev.y, Fv.x, Fv.w};

            bool in[8];
#pragma unroll
            for (int i = 0; i < 8; ++i) {
                const float sq = (X[i] * X[i] + Y[i] * Y[i]) + Z[i] * Z[i];
                const float dt = (qx * X[i] + qy * Y[i]) + qz * Z[i];
                in[i] = ((sqn + sq) - 2.0f * dt) < 256.0f;
            }

            unsigned long long M[8];
#pragma unroll
            for (int i = 0; i < 8; ++i) M[i] = __ballot(in[i]);

            if (cnt == 0) {   // wave-uniform: find global first in-ball index
                int f = 0x7fffffff;
#pragma unroll
                for (int i = 0; i < 8; ++i) {
                    if (M[i]) {
                        const int c = base + 8 * (int)__builtin_ctzll(M[i]) + i;
                        f = f < c ? f : c;
                    }
                }
                if (f != 0x7fffffff) first = f;
            }

            // in-order slot: all hits at lanes < l (any i), plus i' < i here
            int p = cnt;
#pragma unroll
            for (int i = 0; i < 8; ++i) p += (int)__popcll(M[i] & below);
            int s = p;
#pragma unroll
            for (int i = 0; i < 8; ++i) {
                if (in[i]) {
                    if (s > 0 && s < S_ && (s % 5) != 0)
                        out[s - 1 - s / 5] = m0 + i;
                    s += 1;
                }
            }

#pragma unroll
            for (int i = 0; i < 8; ++i) cnt += (int)__popcll(M[i]);
            if (cnt >= S_) break;   // wave-uniform exit
        }

        // pad slots [cnt, 20) with 'first'
        if (lane < S_ && lane >= cnt && lane > 0 && (lane % 5) != 0) {
            out[lane - 1 - lane / 5] = first;
        }
    }
    __syncthreads();   // sidx complete; smem(xyz) still needed below

    // ---------------- xyz gather (reads smem + sidx), nt streamed -----------
    for (int e = t; e < 3 * NW * K_; e += THREADS) {
        const int j  = e >> 9;            // 0..2
        const int r9 = e & 511;
        const int nl = r9 >> 4;
        const int k  = r9 & 15;
        __builtin_nontemporal_store(
            smem[sidx[nl * K_ + k] * 3 + j],
            &out_xyz[((size_t)(b * 3 + j) * N_ + (n0 + nl)) * K_ + k]);
    }

    // ---------------- feature gather: 8 sub-tiles, software-pipelined -------
    const float* fb = feat + (size_t)b * N_ * C_;
    float* ob = out_feat + (size_t)b * C_ * N_ * K_ + (size_t)n0 * K_;

    // per-thread tile slice: 4 float4 (rows r = (t+512i)>>5, cols c0 = (t&31)*4)
    f4 v0, v1, v2, v3;
    const int rr0 = t >> 5,        cc0 = (t & 31) * 4;
    const int rr1 = (t + 512) >> 5;
    const int rr2 = (t + 1024) >> 5;
    const int rr3 = (t + 1536) >> 5;

#define LOADREGS(ST)                                                            \
    do {                                                                        \
        const int s_ = (ST) * NSUB;                                             \
        v0 = *reinterpret_cast<const f4*>(                                      \
            fb + (size_t)sidx[(s_ + (rr0 >> 4)) * K_ + (rr0 & 15)] * C_ + cc0); \
        v1 = *reinterpret_cast<const f4*>(                                      \
            fb + (size_t)sidx[(s_ + (rr1 >> 4)) * K_ + (rr1 & 15)] * C_ + cc0); \
        v2 = *reinterpret_cast<const f4*>(                                      \
            fb + (size_t)sidx[(s_ + (rr2 >> 4)) * K_ + (rr2 & 15)] * C_ + cc0); \
        v3 = *reinterpret_cast<const f4*>(                                      \
            fb + (size_t)sidx[(s_ + (rr3 >> 4)) * K_ + (rr3 & 15)] * C_ + cc0); \
    } while (0)

    LOADREGS(0);   // prologue (reads sidx + global only; smem untouched)

    for (int st = 0; st < NW / NSUB; ++st) {
        __syncthreads();   // previous drain (or xyz gather) done reading smem
        // commit tile st from regs into transpose buffer
        smem[rr0 * LP + cc0 + 0] = v0.x; smem[rr0 * LP + cc0 + 1] = v0.y;
        smem[rr0 * LP + cc0 + 2] = v0.z; smem[rr0 * LP + cc0 + 3] = v0.w;
        smem[rr1 * LP + cc0 + 0] = v1.x; smem[rr1 * LP + cc0 + 1] = v1.y;
        smem[rr1 * LP + cc0 + 2] = v1.z; smem[rr1 * LP + cc0 + 3] = v1.w;
        smem[rr2 * LP + cc0 + 0] = v2.x; smem[rr2 * LP + cc0 + 1] = v2.y;
        smem[rr2 * LP + cc0 + 2] = v2.z; smem[rr2 * LP + cc0 + 3] = v2.w;
        smem[rr3 * LP + cc0 + 0] = v3.x; smem[rr3 * LP + cc0 + 1] = v3.y;
        smem[rr3 * LP + cc0 + 2] = v3.z; smem[rr3 * LP + cc0 + 3] = v3.w;

        if (st + 1 < NW / NSUB) LOADREGS(st + 1);   // L2 latency hides under drain

        __syncthreads();
        // drain: nontemporal float4 stores, 1 KB contiguous per (wave, c);
        // wave64 covers 4 c-streams per inst. LDS read bank =
        // (r4 + j + c) % 32 with LP=129 -> ~2-way, free.
        for (int e = t; e < NSUB * K_ * C_ / 4; e += THREADS) {   // 2048 f4
            const int c  = e >> 4;          // 0..127
            const int r4 = (e & 15) * 4;    // 0,4,...,60
            f4 v;
            v.x = smem[(r4 + 0) * LP + c];
            v.y = smem[(r4 + 1) * LP + c];
            v.z = smem[(r4 + 2) * LP + c];
            v.w = smem[(r4 + 3) * LP + c];
            __builtin_nontemporal_store(
                v, reinterpret_cast<f4*>(
                       ob + (size_t)c * (N_ * K_) + (size_t)(st * NSUB) * K_ + r4));
        }
    }
#undef LOADREGS
}

extern "C" void kernel_launch(void* const* d_in, const int* in_sizes, int n_in,
                              void* d_out, int out_size, void* d_ws, size_t ws_size,
                              hipStream_t stream) {
    const float* xyz  = (const float*)d_in[0];   // (8, 4096, 3)
    const float* feat = (const float*)d_in[1];   // (8, 4096, 128)

    float* out_xyz  = (float*)d_out;                       // (8,3,4096,16)
    float* out_feat = out_xyz + (size_t)B_ * 3 * N_ * K_;  // (8,128,4096,16)

    // one block per (b, 32 consecutive queries); fused, no workspace
    hipLaunchKernelGGL(fused_kernel, dim3(B_ * N_ / NW), dim3(THREADS), 0, stream,
                       xyz, feat, out_xyz, out_feat);
}

// Round 10
// 66.042 us; speedup vs baseline: 2.2460x; 1.2106x over previous
//
#include <hip/hip_runtime.h>
#include <hip/hip_bf16.h>

// Match numpy float32 semantics exactly: no FMA contraction, fixed op order.
#pragma clang fp contract(off)

#define B_ 8
#define N_ 4096
#define C_ 128
#define K_ 16      // SAMPLE (output neighbors)
#define S_ 20      // SAMPLE_NUM (ball_query nsample)
#define NW 8       // queries per block (1 per wave) -> 4096 blocks, ~5 CU
                   // generations: desyncs A/B phases across resident blocks
#define NSUB 4     // queries per LDS transpose pass (2 passes)
#define LP 129     // transpose pitch (words): odd -> conflict-light both sides
#define THREADS 512

typedef float f4 __attribute__((ext_vector_type(4)));

// slot s in [0,20) -> output position k = s - 1 - s/5, valid iff s>0 && s%5!=0

__global__ __launch_bounds__(THREADS, 6) void fused_kernel(const float* __restrict__ xyz,
                                                           const float* __restrict__ feat,
                                                           float* __restrict__ out_xyz,
                                                           float* __restrict__ out_feat) {
#pragma clang fp contract(off)
    // 48 KB union: phase A = whole-batch xyz cache; phase B = transpose buffer
    __shared__ float smem[N_ * 3];
    __shared__ int sidx[NW * K_];

    const int w    = blockIdx.x;        // 0..4095
    const int b    = w & 7;             // XCD-align: batch b lives on XCD b
    const int n0   = (w >> 3) * NW;
    const int t    = threadIdx.x;
    const int wave = t >> 6;            // 0..7
    const int lane = t & 63;
    const float* xb = xyz + (size_t)b * (N_ * 3);

    // ---- stage whole batch xyz into LDS (3072 float4 = 48 KB, coalesced) ----
    {
        const f4* src = reinterpret_cast<const f4*>(xb);
        f4* dst = reinterpret_cast<f4*>(smem);
        for (int i = t; i < N_ * 3 / 4; i += THREADS) dst[i] = src[i];
    }
    __syncthreads();

    // ---------------- Phase A: 1 query per wave, 8 candidates/lane/iter -----
    {
        const int nq = wave;
        const int n  = n0 + nq;
        const float qx = smem[n * 3 + 0];
        const float qy = smem[n * 3 + 1];
        const float qz = smem[n * 3 + 2];
        const float sqn = (qx * qx + qy * qy) + qz * qz;

        int cnt = 0;
        int first = -1;
        int* out = sidx + nq * K_;
        const unsigned long long below = (1ull << lane) - 1ull;

        for (int base = 0; base < N_; base += 512) {
            const int m0 = base + 8 * lane;
            // 96 contiguous bytes per lane: 6 x ds_read_b128 (16B-aligned)
            const f4 A = *reinterpret_cast<const f4*>(&smem[m0 * 3 + 0]);
            const f4 Bv= *reinterpret_cast<const f4*>(&smem[m0 * 3 + 4]);
            const f4 Cv= *reinterpret_cast<const f4*>(&smem[m0 * 3 + 8]);
            const f4 Dv= *reinterpret_cast<const f4*>(&smem[m0 * 3 + 12]);
            const f4 Ev= *reinterpret_cast<const f4*>(&smem[m0 * 3 + 16]);
            const f4 Fv= *reinterpret_cast<const f4*>(&smem[m0 * 3 + 20]);

            const float X[8] = {A.x, A.w, Bv.z, Cv.y, Dv.x, Dv.w, Ev.z, Fv.y};
            const float Y[8] = {A.y, Bv.x, Bv.w, Cv.z, Dv.y, Ev.x, Ev.w, Fv.z};
            const float Z[8] = {A.z, Bv.y, Cv.x, Cv.w, Dv.z, Ev.y, Fv.x, Fv.w};

            bool in[8];
#pragma unroll
            for (int i = 0; i < 8; ++i) {
                const float sq = (X[i] * X[i] + Y[i] * Y[i]) + Z[i] * Z[i];
                const float dt = (qx * X[i] + qy * Y[i]) + qz * Z[i];
                in[i] = ((sqn + sq) - 2.0f * dt) < 256.0f;
            }

            unsigned long long M[8];
#pragma unroll
            for (int i = 0; i < 8; ++i) M[i] = __ballot(in[i]);

            if (cnt == 0) {   // wave-uniform: find global first in-ball index
                int f = 0x7fffffff;
#pragma unroll
                for (int i = 0; i < 8; ++i) {
                    if (M[i]) {
                        const int c = base + 8 * (int)__builtin_ctzll(M[i]) + i;
                        f = f < c ? f : c;
                    }
                }
                if (f != 0x7fffffff) first = f;
            }

            // in-order slot: all hits at lanes < l (any i), plus i' < i here
            int p = cnt;
#pragma unroll
            for (int i = 0; i < 8; ++i) p += (int)__popcll(M[i] & below);
            int s = p;
#pragma unroll
            for (int i = 0; i < 8; ++i) {
                if (in[i]) {
                    if (s > 0 && s < S_ && (s % 5) != 0)
                        out[s - 1 - s / 5] = m0 + i;
                    s += 1;
                }
            }

#pragma unroll
            for (int i = 0; i < 8; ++i) cnt += (int)__popcll(M[i]);
            if (cnt >= S_) break;   // wave-uniform exit
        }

        // pad slots [cnt, 20) with 'first'
        if (lane < S_ && lane >= cnt && lane > 0 && (lane % 5) != 0) {
            out[lane - 1 - lane / 5] = first;
        }
    }
    __syncthreads();   // sidx complete; smem(xyz) still needed below

    // ---------------- xyz gather (reads smem + sidx), nt streamed -----------
    if (t < 3 * NW * K_) {                 // 384 threads
        const int j  = t >> 7;             // 0..2
        const int r  = t & 127;
        const int nl = r >> 4;             // 0..7
        const int k  = r & 15;
        __builtin_nontemporal_store(
            smem[sidx[nl * K_ + k] * 3 + j],
            &out_xyz[((size_t)(b * 3 + j) * N_ + (n0 + nl)) * K_ + k]);
    }

    // ---------------- feature gather: 2 sub-tiles, software-pipelined -------
    const float* fb = feat + (size_t)b * N_ * C_;
    float* ob = out_feat + (size_t)b * C_ * N_ * K_ + (size_t)n0 * K_;

    // per-thread tile slice: 4 float4 (rows r = (t+512i)>>5, cols c0 = (t&31)*4)
    f4 v0, v1, v2, v3;
    const int rr0 = t >> 5,        cc0 = (t & 31) * 4;
    const int rr1 = (t + 512) >> 5;
    const int rr2 = (t + 1024) >> 5;
    const int rr3 = (t + 1536) >> 5;

#define LOADREGS(ST)                                                            \
    do {                                                                        \
        const int s_ = (ST) * NSUB;                                             \
        v0 = *reinterpret_cast<const f4*>(                                      \
            fb + (size_t)sidx[(s_ + (rr0 >> 4)) * K_ + (rr0 & 15)] * C_ + cc0); \
        v1 = *reinterpret_cast<const f4*>(                                      \
            fb + (size_t)sidx[(s_ + (rr1 >> 4)) * K_ + (rr1 & 15)] * C_ + cc0); \
        v2 = *reinterpret_cast<const f4*>(                                      \
            fb + (size_t)sidx[(s_ + (rr2 >> 4)) * K_ + (rr2 & 15)] * C_ + cc0); \
        v3 = *reinterpret_cast<const f4*>(                                      \
            fb + (size_t)sidx[(s_ + (rr3 >> 4)) * K_ + (rr3 & 15)] * C_ + cc0); \
    } while (0)

    LOADREGS(0);   // prologue (reads sidx + global only; smem untouched)

    for (int st = 0; st < NW / NSUB; ++st) {
        __syncthreads();   // previous drain (or xyz gather) done reading smem
        // commit tile st from regs into transpose buffer
        smem[rr0 * LP + cc0 + 0] = v0.x; smem[rr0 * LP + cc0 + 1] = v0.y;
        smem[rr0 * LP + cc0 + 2] = v0.z; smem[rr0 * LP + cc0 + 3] = v0.w;
        smem[rr1 * LP + cc0 + 0] = v1.x; smem[rr1 * LP + cc0 + 1] = v1.y;
        smem[rr1 * LP + cc0 + 2] = v1.z; smem[rr1 * LP + cc0 + 3] = v1.w;
        smem[rr2 * LP + cc0 + 0] = v2.x; smem[rr2 * LP + cc0 + 1] = v2.y;
        smem[rr2 * LP + cc0 + 2] = v2.z; smem[rr2 * LP + cc0 + 3] = v2.w;
        smem[rr3 * LP + cc0 + 0] = v3.x; smem[rr3 * LP + cc0 + 1] = v3.y;
        smem[rr3 * LP + cc0 + 2] = v3.z; smem[rr3 * LP + cc0 + 3] = v3.w;

        if (st + 1 < NW / NSUB) LOADREGS(st + 1);   // L2 latency hides under drain

        __syncthreads();
        // drain: nontemporal float4 stores, contiguous 64B per 4 rows;
        // LDS read bank = (r4 + c) % 32 with LP=129 -> ~2-way, free.
        for (int e = t; e < NSUB * K_ * C_ / 4; e += THREADS) {   // 2048 f4
            const int c  = e >> 4;          // 0..127
            const int r4 = (e & 15) * 4;    // 0,4,...,60
            f4 v;
            v.x = smem[(r4 + 0) * LP + c];
            v.y = smem[(r4 + 1) * LP + c];
            v.z = smem[(r4 + 2) * LP + c];
            v.w = smem[(r4 + 3) * LP + c];
            __builtin_nontemporal_store(
                v, reinterpret_cast<f4*>(
                       ob + (size_t)c * (N_ * K_) + (size_t)(st * NSUB) * K_ + r4));
        }
    }
#undef LOADREGS
}

extern "C" void kernel_launch(void* const* d_in, const int* in_sizes, int n_in,
                              void* d_out, int out_size, void* d_ws, size_t ws_size,
                              hipStream_t stream) {
    const float* xyz  = (const float*)d_in[0];   // (8, 4096, 3)
    const float* feat = (const float*)d_in[1];   // (8, 4096, 128)

    float* out_xyz  = (float*)d_out;                       // (8,3,4096,16)
    float* out_feat = out_xyz + (size_t)B_ * 3 * N_ * K_;  // (8,128,4096,16)

    // one block per (b, 8 consecutive queries); fused, no workspace
    hipLaunchKernelGGL(fused_kernel, dim3(B_ * N_ / NW), dim3(THREADS), 0, stream,
                       xyz, feat, out_xyz, out_feat);
}